// Round 1
// baseline (743.578 us; speedup 1.0000x reference)
//
#include <hip/hip_runtime.h>
#include <math.h>

#define FIN   512
#define H1DIM 256
#define HEADS 4
#define CH    64
#define OUTC  40
#define NEG   0.2f
#define EPSV  1e-16f

__device__ __forceinline__ float leaky(float a) { return a > 0.f ? a : NEG * a; }

// ---------------------------------------------------------------------------
// GEMM1: h1[N,256] = x[N,512] @ W1[512,256]   (fp32, 64x256 tile, 8x8/thread)
// ---------------------------------------------------------------------------
__global__ __launch_bounds__(256) void gemm1_kernel(
    const float* __restrict__ x, const float* __restrict__ W1,
    float* __restrict__ h1, int N)
{
    __shared__ float As[16][68];    // transposed x tile: As[k][m], pad 68 (16B-aligned rows)
    __shared__ float Bs[16][256];   // W1 tile: Bs[k][n]

    const int tid = threadIdx.x;
    const int tx = tid & 31;        // col group 0..31
    const int ty = tid >> 5;        // row group 0..7
    const int row0 = blockIdx.x * 64;

    float acc[8][8];
#pragma unroll
    for (int i = 0; i < 8; ++i)
#pragma unroll
        for (int j = 0; j < 8; ++j) acc[i][j] = 0.f;

    const int arow = row0 + (tid >> 2);
    const int asrc = arow < N ? arow : (N - 1);   // clamp (stores are guarded)
    const int ak   = (tid & 3) * 4;
    const int brow = tid >> 4;          // 0..15
    const int bcol = (tid & 15) * 4;    // 0..60

    for (int k0 = 0; k0 < FIN; k0 += 16) {
        float4 av  = *(const float4*)&x[(size_t)asrc * FIN + k0 + ak];
        float4 bv0 = *(const float4*)&W1[(size_t)(k0 + brow) * H1DIM + bcol];
        float4 bv1 = *(const float4*)&W1[(size_t)(k0 + brow) * H1DIM + bcol + 64];
        float4 bv2 = *(const float4*)&W1[(size_t)(k0 + brow) * H1DIM + bcol + 128];
        float4 bv3 = *(const float4*)&W1[(size_t)(k0 + brow) * H1DIM + bcol + 192];

        As[ak + 0][tid >> 2] = av.x;
        As[ak + 1][tid >> 2] = av.y;
        As[ak + 2][tid >> 2] = av.z;
        As[ak + 3][tid >> 2] = av.w;
        *(float4*)&Bs[brow][bcol]       = bv0;
        *(float4*)&Bs[brow][bcol + 64]  = bv1;
        *(float4*)&Bs[brow][bcol + 128] = bv2;
        *(float4*)&Bs[brow][bcol + 192] = bv3;
        __syncthreads();

#pragma unroll
        for (int k = 0; k < 16; ++k) {
            float4 a0 = *(float4*)&As[k][ty * 8];
            float4 a1 = *(float4*)&As[k][ty * 8 + 4];
            float4 b0 = *(float4*)&Bs[k][tx * 4];
            float4 b1 = *(float4*)&Bs[k][128 + tx * 4];
            float a[8] = { a0.x, a0.y, a0.z, a0.w, a1.x, a1.y, a1.z, a1.w };
            float b[8] = { b0.x, b0.y, b0.z, b0.w, b1.x, b1.y, b1.z, b1.w };
#pragma unroll
            for (int i = 0; i < 8; ++i)
#pragma unroll
                for (int j = 0; j < 8; ++j) acc[i][j] += a[i] * b[j];
        }
        __syncthreads();
    }

#pragma unroll
    for (int i = 0; i < 8; ++i) {
        int r = row0 + ty * 8 + i;
        if (r < N) {
            *(float4*)&h1[(size_t)r * H1DIM + tx * 4] =
                make_float4(acc[i][0], acc[i][1], acc[i][2], acc[i][3]);
            *(float4*)&h1[(size_t)r * H1DIM + 128 + tx * 4] =
                make_float4(acc[i][4], acc[i][5], acc[i][6], acc[i][7]);
        }
    }
}

// ---------------------------------------------------------------------------
// scores1: a_src1[n,h] = dot(h1[n,h,:], att_src1[h,:]) ; same for dst
// thread per (n,h)
// ---------------------------------------------------------------------------
__global__ void scores1_kernel(
    const float* __restrict__ h1, const float* __restrict__ attS,
    const float* __restrict__ attD, float* __restrict__ aS,
    float* __restrict__ aD, int N)
{
    int i = blockIdx.x * blockDim.x + threadIdx.x;
    if (i >= N * HEADS) return;
    int n = i >> 2, h = i & 3;
    const float* hp = h1 + (size_t)n * H1DIM + h * CH;
    const float* sp = attS + h * CH;
    const float* dp = attD + h * CH;
    float s = 0.f, d = 0.f;
#pragma unroll
    for (int c = 0; c < CH; c += 4) {
        float4 v = *(const float4*)&hp[c];
        float4 a = *(const float4*)&sp[c];
        float4 b = *(const float4*)&dp[c];
        s += v.x * a.x + v.y * a.y + v.z * a.z + v.w * a.w;
        d += v.x * b.x + v.y * b.y + v.z * b.z + v.w * b.w;
    }
    aS[i] = s;
    aD[i] = d;
}

// ---------------------------------------------------------------------------
// CSR build: count degrees by dst (self-loops are edges [E, E+N))
// ---------------------------------------------------------------------------
__global__ void degcount_kernel(const int* __restrict__ ei, int* __restrict__ deg,
                                int E, int Etot)
{
    int e = blockIdx.x * 256 + threadIdx.x;
    if (e >= Etot) return;
    int d = (e < E) ? ei[E + e] : (e - E);
    atomicAdd(&deg[d], 1);
}

// single-block chunked scan: offsets[0]=0, offsets[i+1]=sum(deg[0..i])
__global__ __launch_bounds__(1024) void scan_kernel(
    const int* __restrict__ deg, int* __restrict__ offsets, int N)
{
    __shared__ int wsums[16];
    __shared__ int excl[16];
    __shared__ int btot;
    __shared__ int carry;
    int tid = threadIdx.x, lane = tid & 63, wid = tid >> 6;
    if (tid == 0) { carry = 0; offsets[0] = 0; }
    __syncthreads();
    for (int base = 0; base < N; base += 1024) {
        int idx = base + tid;
        int v = (idx < N) ? deg[idx] : 0;
        int sv = v;
#pragma unroll
        for (int off = 1; off < 64; off <<= 1) {
            int t = __shfl_up(sv, off, 64);
            if (lane >= off) sv += t;
        }
        if (lane == 63) wsums[wid] = sv;
        __syncthreads();
        if (wid == 0 && lane < 16) {
            int wv = wsums[lane];
            int sw = wv;
#pragma unroll
            for (int off = 1; off < 16; off <<= 1) {
                int t = __shfl_up(sw, off, 64);
                if (lane >= off) sw += t;
            }
            excl[lane] = sw - wv;
            if (lane == 15) btot = sw;
        }
        __syncthreads();
        int res = sv + excl[wid] + carry;
        if (idx < N) offsets[idx + 1] = res;
        __syncthreads();
        if (tid == 0) carry += btot;
    }
}

__global__ void scatter_kernel(const int* __restrict__ ei, const int* __restrict__ offsets,
                               int* __restrict__ cursor, int* __restrict__ csr_src,
                               int E, int Etot)
{
    int e = blockIdx.x * 256 + threadIdx.x;
    if (e >= Etot) return;
    int s, d;
    if (e < E) { s = ei[e]; d = ei[E + e]; }
    else       { s = e - E; d = s; }
    int pos = offsets[d] + atomicAdd(&cursor[d], 1);
    csr_src[pos] = s;
}

// ---------------------------------------------------------------------------
// agg1: wave per node. Pass1 segment-max; pass2 exp/denom + weighted gather of
// h1[src] rows; epilogue: /denom, +b1, ELU -> g1
// ---------------------------------------------------------------------------
__global__ __launch_bounds__(256) void agg1_kernel(
    const float* __restrict__ h1, const float* __restrict__ aS,
    const float* __restrict__ aD, const int* __restrict__ offsets,
    const int* __restrict__ csr_src, const float* __restrict__ b1,
    float* __restrict__ g1, int N)
{
    int lane = threadIdx.x & 63, wid = threadIdx.x >> 6;
    int n = blockIdx.x * 4 + wid;
    if (n >= N) return;
    int start = offsets[n], end = offsets[n + 1];
    float4 ad = *(const float4*)&aD[(size_t)n * 4];

    float m0 = -INFINITY, m1 = -INFINITY, m2 = -INFINITY, m3 = -INFINITY;
    for (int p = start + lane; p < end; p += 64) {
        int s = csr_src[p];
        float4 as = *(const float4*)&aS[(size_t)s * 4];
        m0 = fmaxf(m0, leaky(as.x + ad.x));
        m1 = fmaxf(m1, leaky(as.y + ad.y));
        m2 = fmaxf(m2, leaky(as.z + ad.z));
        m3 = fmaxf(m3, leaky(as.w + ad.w));
    }
#pragma unroll
    for (int off = 32; off > 0; off >>= 1) {
        m0 = fmaxf(m0, __shfl_xor(m0, off));
        m1 = fmaxf(m1, __shfl_xor(m1, off));
        m2 = fmaxf(m2, __shfl_xor(m2, off));
        m3 = fmaxf(m3, __shfl_xor(m3, off));
    }
    int h = lane >> 4;
    float mh  = (h == 0) ? m0 : (h == 1) ? m1 : (h == 2) ? m2 : m3;
    float adh = (h == 0) ? ad.x : (h == 1) ? ad.y : (h == 2) ? ad.z : ad.w;

    float ac0 = 0.f, ac1 = 0.f, ac2 = 0.f, ac3 = 0.f, denom = 0.f;
    int cbase = lane * 4;
    for (int p = start; p < end; ++p) {
        int s = csr_src[p];
        float a = leaky(aS[(size_t)s * 4 + h] + adh);
        float ex = __expf(a - mh);
        denom += ex;
        float4 hv = *(const float4*)&h1[(size_t)s * H1DIM + cbase];
        ac0 += ex * hv.x;
        ac1 += ex * hv.y;
        ac2 += ex * hv.z;
        ac3 += ex * hv.w;
    }
    float inv = 1.f / (denom + EPSV);
    float4 bb = *(const float4*)&b1[cbase];
    float v0 = ac0 * inv + bb.x;
    float v1 = ac1 * inv + bb.y;
    float v2 = ac2 * inv + bb.z;
    float v3 = ac3 * inv + bb.w;
    v0 = v0 > 0.f ? v0 : expm1f(v0);
    v1 = v1 > 0.f ? v1 : expm1f(v1);
    v2 = v2 > 0.f ? v2 : expm1f(v2);
    v3 = v3 > 0.f ? v3 : expm1f(v3);
    *(float4*)&g1[(size_t)n * H1DIM + cbase] = make_float4(v0, v1, v2, v3);
}

// ---------------------------------------------------------------------------
// GEMM2: h2[N,40] = g1[N,256] @ W2[256,40]; fused a_src2/a_dst2 reductions.
// wave handles 8 nodes; rows staged in LDS; lane = output channel.
// ---------------------------------------------------------------------------
__global__ __launch_bounds__(256) void gemm2_kernel(
    const float* __restrict__ g1, const float* __restrict__ W2,
    const float* __restrict__ attS2, const float* __restrict__ attD2,
    float* __restrict__ h2, float* __restrict__ aS2, float* __restrict__ aD2, int N)
{
    __shared__ float rows[4][8][256];
    int lane = threadIdx.x & 63, wid = threadIdx.x >> 6;
    int nbase = blockIdx.x * 32 + wid * 8;
    bool act = lane < OUTC;
    int cc = act ? lane : 0;
    float attS = act ? attS2[lane] : 0.f;
    float attD = act ? attD2[lane] : 0.f;

#pragma unroll
    for (int i = 0; i < 8; ++i) {
        int n = nbase + i;
        float4 v = make_float4(0.f, 0.f, 0.f, 0.f);
        if (n < N) v = *(const float4*)&g1[(size_t)n * H1DIM + lane * 4];
        *(float4*)&rows[wid][i][lane * 4] = v;
    }

    float acc[8];
#pragma unroll
    for (int i = 0; i < 8; ++i) acc[i] = 0.f;

    for (int k = 0; k < H1DIM; k += 4) {
        float w0 = W2[(size_t)(k + 0) * OUTC + cc];
        float w1 = W2[(size_t)(k + 1) * OUTC + cc];
        float w2 = W2[(size_t)(k + 2) * OUTC + cc];
        float w3 = W2[(size_t)(k + 3) * OUTC + cc];
#pragma unroll
        for (int i = 0; i < 8; ++i) {
            float4 g = *(const float4*)&rows[wid][i][k];
            acc[i] += g.x * w0 + g.y * w1 + g.z * w2 + g.w * w3;
        }
    }

#pragma unroll
    for (int i = 0; i < 8; ++i) {
        int n = nbase + i;
        if (n >= N) continue;   // wave-uniform
        if (act) h2[(size_t)n * OUTC + lane] = acc[i];
        float ts = act ? acc[i] * attS : 0.f;
        float td = act ? acc[i] * attD : 0.f;
#pragma unroll
        for (int off = 32; off > 0; off >>= 1) {
            ts += __shfl_xor(ts, off);
            td += __shfl_xor(td, off);
        }
        if (lane == 0) { aS2[n] = ts; aD2[n] = td; }
    }
}

// ---------------------------------------------------------------------------
// agg2: wave per node, H=1, C=40, fused bias + log_softmax
// ---------------------------------------------------------------------------
__global__ __launch_bounds__(256) void agg2_kernel(
    const float* __restrict__ h2, const float* __restrict__ aS2,
    const float* __restrict__ aD2, const int* __restrict__ offsets,
    const int* __restrict__ csr_src, const float* __restrict__ b2,
    float* __restrict__ out, int N)
{
    int lane = threadIdx.x & 63, wid = threadIdx.x >> 6;
    int n = blockIdx.x * 4 + wid;
    if (n >= N) return;
    int start = offsets[n], end = offsets[n + 1];
    float ad = aD2[n];

    float m = -INFINITY;
    for (int p = start + lane; p < end; p += 64)
        m = fmaxf(m, leaky(aS2[csr_src[p]] + ad));
#pragma unroll
    for (int off = 32; off > 0; off >>= 1) m = fmaxf(m, __shfl_xor(m, off));

    bool act = lane < OUTC;
    float acc = 0.f, denom = 0.f;
    for (int p = start; p < end; ++p) {
        int s = csr_src[p];
        float ex = __expf(leaky(aS2[s] + ad) - m);
        denom += ex;
        float hv = act ? h2[(size_t)s * OUTC + lane] : 0.f;
        acc += ex * hv;
    }
    float v = acc / (denom + EPSV) + (act ? b2[lane] : 0.f);

    float vm = act ? v : -INFINITY;
#pragma unroll
    for (int off = 32; off > 0; off >>= 1) vm = fmaxf(vm, __shfl_xor(vm, off));
    float ex2 = act ? __expf(v - vm) : 0.f;
    float tot = ex2;
#pragma unroll
    for (int off = 32; off > 0; off >>= 1) tot += __shfl_xor(tot, off);
    float res = v - vm - __logf(tot);
    if (act) out[(size_t)n * OUTC + lane] = res;
}

// ---------------------------------------------------------------------------
extern "C" void kernel_launch(void* const* d_in, const int* in_sizes, int n_in,
                              void* d_out, int out_size, void* d_ws, size_t ws_size,
                              hipStream_t stream)
{
    const float* x     = (const float*)d_in[0];
    const int*   ei    = (const int*)d_in[1];
    const float* W1    = (const float*)d_in[2];
    const float* attS1 = (const float*)d_in[3];
    const float* attD1 = (const float*)d_in[4];
    const float* b1    = (const float*)d_in[5];
    const float* W2    = (const float*)d_in[6];
    const float* attS2 = (const float*)d_in[7];
    const float* attD2 = (const float*)d_in[8];
    const float* b2    = (const float*)d_in[9];
    float* out = (float*)d_out;

    const int N    = in_sizes[0] / FIN;
    const int E    = in_sizes[1] / 2;
    const int Etot = E + N;

    char* ws = (char*)d_ws;
    size_t off = 0;
    auto take = [&](size_t bytes) -> char* {
        char* p = ws + off;
        off = (off + bytes + 255) & ~(size_t)255;
        return p;
    };
    float* h1      = (float*)take((size_t)N * H1DIM * 4);
    float* g1      = (float*)take((size_t)N * H1DIM * 4);
    float* aS1     = (float*)take((size_t)N * 4 * 4);
    float* aD1     = (float*)take((size_t)N * 4 * 4);
    float* h2      = (float*)take((size_t)N * OUTC * 4);
    float* aS2v    = (float*)take((size_t)N * 4);
    float* aD2v    = (float*)take((size_t)N * 4);
    int*   deg     = (int*)take((size_t)N * 4);
    int*   offsets = (int*)take((size_t)(N + 1) * 4);
    int*   cursor  = (int*)take((size_t)N * 4);
    int*   csr_src = (int*)take((size_t)Etot * 4);

    hipMemsetAsync(deg, 0, (size_t)N * 4, stream);
    hipMemsetAsync(cursor, 0, (size_t)N * 4, stream);

    gemm1_kernel<<<(N + 63) / 64, 256, 0, stream>>>(x, W1, h1, N);
    scores1_kernel<<<(N * HEADS + 255) / 256, 256, 0, stream>>>(h1, attS1, attD1, aS1, aD1, N);
    degcount_kernel<<<(Etot + 255) / 256, 256, 0, stream>>>(ei, deg, E, Etot);
    scan_kernel<<<1, 1024, 0, stream>>>(deg, offsets, N);
    scatter_kernel<<<(Etot + 255) / 256, 256, 0, stream>>>(ei, offsets, cursor, csr_src, E, Etot);
    agg1_kernel<<<(N + 3) / 4, 256, 0, stream>>>(h1, aS1, aD1, offsets, csr_src, b1, g1, N);
    gemm2_kernel<<<(N + 31) / 32, 256, 0, stream>>>(g1, W2, attS2, attD2, h2, aS2v, aD2v, N);
    agg2_kernel<<<(N + 3) / 4, 256, 0, stream>>>(h2, aS2v, aD2v, offsets, csr_src, b2, out, N);
}

// Round 2
// 669.574 us; speedup vs baseline: 1.1105x; 1.1105x over previous
//
#include <hip/hip_runtime.h>
#include <math.h>

#define FIN   512
#define H1DIM 256
#define HEADS 4
#define CH    64
#define OUTC  40
#define NEG   0.2f
#define EPSV  1e-16f

__device__ __forceinline__ float leaky(float a) { return a > 0.f ? a : NEG * a; }

// round-to-nearest-even float -> bf16 (as short)
__device__ __forceinline__ short f2bf(float f) {
    unsigned u = __builtin_bit_cast(unsigned, f);
    u += 0x7FFFu + ((u >> 16) & 1u);
    return (short)(u >> 16);
}

typedef __attribute__((ext_vector_type(8))) short short8;
typedef __attribute__((ext_vector_type(4))) float float4_t;

// ---------------------------------------------------------------------------
// W1 [512,256] fp32 -> w1t [256,512] bf16 (transposed)
// ---------------------------------------------------------------------------
__global__ void cvt_w1_kernel(const float* __restrict__ W1, short* __restrict__ w1t)
{
    int idx = blockIdx.x * 256 + threadIdx.x;
    if (idx >= FIN * H1DIM) return;
    int k = idx >> 8;          // /256
    int n = idx & 255;
    w1t[(size_t)n * FIN + k] = f2bf(W1[idx]);
}

// ---------------------------------------------------------------------------
// GEMM1 (MFMA bf16): h1[N,256] = x[N,512] @ W1[512,256]
// block=256 (4 waves). M-tile 64 rows; wave w covers cols w*64 (4x4 16x16 tiles).
// A: fp32 global loads + in-register cvt to bf16. B: w1t bf16 (L2-resident).
// Fragment layout (verified m89/m91): A[m=lane&15][k=(lane>>4)*8+j],
// C/D: col=lane&15, row=(lane>>4)*4+reg.
// ---------------------------------------------------------------------------
__global__ __launch_bounds__(256) void gemm1_mfma_kernel(
    const float* __restrict__ x, const short* __restrict__ w1t,
    float* __restrict__ h1, int N)
{
    const int lane = threadIdx.x & 63;
    const int wid  = threadIdx.x >> 6;
    const int row0 = blockIdx.x * 64;
    const int col0 = wid * 64;
    const int quad = lane >> 4;   // 0..3
    const int m16  = lane & 15;

    float4_t acc[4][4];
#pragma unroll
    for (int i = 0; i < 4; ++i)
#pragma unroll
        for (int j = 0; j < 4; ++j) acc[i][j] = (float4_t){0.f, 0.f, 0.f, 0.f};

    const float* aptr[4];
#pragma unroll
    for (int i = 0; i < 4; ++i) {
        int r = row0 + i * 16 + m16;
        if (r >= N) r = N - 1;              // clamp; stores are guarded
        aptr[i] = x + (size_t)r * FIN + quad * 8;
    }
    const short* bptr[4];
#pragma unroll
    for (int j = 0; j < 4; ++j) {
        int c = col0 + j * 16 + m16;
        bptr[j] = w1t + (size_t)c * FIN + quad * 8;
    }

    for (int k = 0; k < FIN; k += 32) {
        short8 a[4], b[4];
#pragma unroll
        for (int i = 0; i < 4; ++i) {
            float4 f0 = *(const float4*)(aptr[i] + k);
            float4 f1 = *(const float4*)(aptr[i] + k + 4);
            short8 t;
            t[0] = f2bf(f0.x); t[1] = f2bf(f0.y); t[2] = f2bf(f0.z); t[3] = f2bf(f0.w);
            t[4] = f2bf(f1.x); t[5] = f2bf(f1.y); t[6] = f2bf(f1.z); t[7] = f2bf(f1.w);
            a[i] = t;
        }
#pragma unroll
        for (int j = 0; j < 4; ++j)
            b[j] = *(const short8*)(bptr[j] + k);
#pragma unroll
        for (int i = 0; i < 4; ++i)
#pragma unroll
            for (int j = 0; j < 4; ++j)
                acc[i][j] = __builtin_amdgcn_mfma_f32_16x16x32_bf16(a[i], b[j], acc[i][j], 0, 0, 0);
    }

#pragma unroll
    for (int i = 0; i < 4; ++i) {
#pragma unroll
        for (int r = 0; r < 4; ++r) {
            int row = row0 + i * 16 + quad * 4 + r;
            if (row < N) {
#pragma unroll
                for (int j = 0; j < 4; ++j)
                    h1[(size_t)row * H1DIM + col0 + j * 16 + m16] = acc[i][j][r];
            }
        }
    }
}

// ---------------------------------------------------------------------------
// scores1: a_src1[n,h] = dot(h1[n,h,:], att_src1[h,:]) ; same for dst
// ---------------------------------------------------------------------------
__global__ void scores1_kernel(
    const float* __restrict__ h1, const float* __restrict__ attS,
    const float* __restrict__ attD, float* __restrict__ aS,
    float* __restrict__ aD, int N)
{
    int i = blockIdx.x * blockDim.x + threadIdx.x;
    if (i >= N * HEADS) return;
    int n = i >> 2, h = i & 3;
    const float* hp = h1 + (size_t)n * H1DIM + h * CH;
    const float* sp = attS + h * CH;
    const float* dp = attD + h * CH;
    float s = 0.f, d = 0.f;
#pragma unroll
    for (int c = 0; c < CH; c += 4) {
        float4 v = *(const float4*)&hp[c];
        float4 a = *(const float4*)&sp[c];
        float4 b = *(const float4*)&dp[c];
        s += v.x * a.x + v.y * a.y + v.z * a.z + v.w * a.w;
        d += v.x * b.x + v.y * b.y + v.z * b.z + v.w * b.w;
    }
    aS[i] = s;
    aD[i] = d;
}

// ---------------------------------------------------------------------------
// CSR build
// ---------------------------------------------------------------------------
__global__ void degcount_kernel(const int* __restrict__ ei, int* __restrict__ deg,
                                int E, int Etot)
{
    int e = blockIdx.x * 256 + threadIdx.x;
    if (e >= Etot) return;
    int d = (e < E) ? ei[E + e] : (e - E);
    atomicAdd(&deg[d], 1);
}

__global__ __launch_bounds__(1024) void scan_kernel(
    const int* __restrict__ deg, int* __restrict__ offsets, int N)
{
    __shared__ int wsums[16];
    __shared__ int excl[16];
    __shared__ int btot;
    __shared__ int carry;
    int tid = threadIdx.x, lane = tid & 63, wid = tid >> 6;
    if (tid == 0) { carry = 0; offsets[0] = 0; }
    __syncthreads();
    for (int base = 0; base < N; base += 1024) {
        int idx = base + tid;
        int v = (idx < N) ? deg[idx] : 0;
        int sv = v;
#pragma unroll
        for (int off = 1; off < 64; off <<= 1) {
            int t = __shfl_up(sv, off, 64);
            if (lane >= off) sv += t;
        }
        if (lane == 63) wsums[wid] = sv;
        __syncthreads();
        if (wid == 0 && lane < 16) {
            int wv = wsums[lane];
            int sw = wv;
#pragma unroll
            for (int off = 1; off < 16; off <<= 1) {
                int t = __shfl_up(sw, off, 64);
                if (lane >= off) sw += t;
            }
            excl[lane] = sw - wv;
            if (lane == 15) btot = sw;
        }
        __syncthreads();
        int res = sv + excl[wid] + carry;
        if (idx < N) offsets[idx + 1] = res;
        __syncthreads();
        if (tid == 0) carry += btot;
    }
}

__global__ void scatter_kernel(const int* __restrict__ ei, const int* __restrict__ offsets,
                               int* __restrict__ cursor, int* __restrict__ csr_src,
                               int E, int Etot)
{
    int e = blockIdx.x * 256 + threadIdx.x;
    if (e >= Etot) return;
    int s, d;
    if (e < E) { s = ei[e]; d = ei[E + e]; }
    else       { s = e - E; d = s; }
    int pos = offsets[d] + atomicAdd(&cursor[d], 1);
    csr_src[pos] = s;
}

// ---------------------------------------------------------------------------
// agg1: wave per node; softmax over incoming edges; weighted gather of h1 rows
// ---------------------------------------------------------------------------
__global__ __launch_bounds__(256) void agg1_kernel(
    const float* __restrict__ h1, const float* __restrict__ aS,
    const float* __restrict__ aD, const int* __restrict__ offsets,
    const int* __restrict__ csr_src, const float* __restrict__ b1,
    float* __restrict__ g1, int N)
{
    int lane = threadIdx.x & 63, wid = threadIdx.x >> 6;
    int n = blockIdx.x * 4 + wid;
    if (n >= N) return;
    int start = offsets[n], end = offsets[n + 1];
    float4 ad = *(const float4*)&aD[(size_t)n * 4];

    float m0 = -INFINITY, m1 = -INFINITY, m2 = -INFINITY, m3 = -INFINITY;
    for (int p = start + lane; p < end; p += 64) {
        int s = csr_src[p];
        float4 as = *(const float4*)&aS[(size_t)s * 4];
        m0 = fmaxf(m0, leaky(as.x + ad.x));
        m1 = fmaxf(m1, leaky(as.y + ad.y));
        m2 = fmaxf(m2, leaky(as.z + ad.z));
        m3 = fmaxf(m3, leaky(as.w + ad.w));
    }
#pragma unroll
    for (int off = 32; off > 0; off >>= 1) {
        m0 = fmaxf(m0, __shfl_xor(m0, off));
        m1 = fmaxf(m1, __shfl_xor(m1, off));
        m2 = fmaxf(m2, __shfl_xor(m2, off));
        m3 = fmaxf(m3, __shfl_xor(m3, off));
    }
    int h = lane >> 4;
    float mh  = (h == 0) ? m0 : (h == 1) ? m1 : (h == 2) ? m2 : m3;
    float adh = (h == 0) ? ad.x : (h == 1) ? ad.y : (h == 2) ? ad.z : ad.w;

    float ac0 = 0.f, ac1 = 0.f, ac2 = 0.f, ac3 = 0.f, denom = 0.f;
    int cbase = lane * 4;
    for (int p = start; p < end; ++p) {
        int s = csr_src[p];
        float a = leaky(aS[(size_t)s * 4 + h] + adh);
        float ex = __expf(a - mh);
        denom += ex;
        float4 hv = *(const float4*)&h1[(size_t)s * H1DIM + cbase];
        ac0 += ex * hv.x;
        ac1 += ex * hv.y;
        ac2 += ex * hv.z;
        ac3 += ex * hv.w;
    }
    float inv = 1.f / (denom + EPSV);
    float4 bb = *(const float4*)&b1[cbase];
    float v0 = ac0 * inv + bb.x;
    float v1 = ac1 * inv + bb.y;
    float v2 = ac2 * inv + bb.z;
    float v3 = ac3 * inv + bb.w;
    v0 = v0 > 0.f ? v0 : expm1f(v0);
    v1 = v1 > 0.f ? v1 : expm1f(v1);
    v2 = v2 > 0.f ? v2 : expm1f(v2);
    v3 = v3 > 0.f ? v3 : expm1f(v3);
    *(float4*)&g1[(size_t)n * H1DIM + cbase] = make_float4(v0, v1, v2, v3);
}

// ---------------------------------------------------------------------------
// GEMM2: h2[N,40] = g1[N,256] @ W2[256,40]; fused a_src2/a_dst2 reductions
// ---------------------------------------------------------------------------
__global__ __launch_bounds__(256) void gemm2_kernel(
    const float* __restrict__ g1, const float* __restrict__ W2,
    const float* __restrict__ attS2, const float* __restrict__ attD2,
    float* __restrict__ h2, float* __restrict__ aS2, float* __restrict__ aD2, int N)
{
    __shared__ float rows[4][8][256];
    int lane = threadIdx.x & 63, wid = threadIdx.x >> 6;
    int nbase = blockIdx.x * 32 + wid * 8;
    bool act = lane < OUTC;
    int cc = act ? lane : 0;
    float attS = act ? attS2[lane] : 0.f;
    float attD = act ? attD2[lane] : 0.f;

#pragma unroll
    for (int i = 0; i < 8; ++i) {
        int n = nbase + i;
        float4 v = make_float4(0.f, 0.f, 0.f, 0.f);
        if (n < N) v = *(const float4*)&g1[(size_t)n * H1DIM + lane * 4];
        *(float4*)&rows[wid][i][lane * 4] = v;
    }

    float acc[8];
#pragma unroll
    for (int i = 0; i < 8; ++i) acc[i] = 0.f;

    for (int k = 0; k < H1DIM; k += 4) {
        float w0 = W2[(size_t)(k + 0) * OUTC + cc];
        float w1 = W2[(size_t)(k + 1) * OUTC + cc];
        float w2 = W2[(size_t)(k + 2) * OUTC + cc];
        float w3 = W2[(size_t)(k + 3) * OUTC + cc];
#pragma unroll
        for (int i = 0; i < 8; ++i) {
            float4 g = *(const float4*)&rows[wid][i][k];
            acc[i] += g.x * w0 + g.y * w1 + g.z * w2 + g.w * w3;
        }
    }

#pragma unroll
    for (int i = 0; i < 8; ++i) {
        int n = nbase + i;
        if (n >= N) continue;   // wave-uniform
        if (act) h2[(size_t)n * OUTC + lane] = acc[i];
        float ts = act ? acc[i] * attS : 0.f;
        float td = act ? acc[i] * attD : 0.f;
#pragma unroll
        for (int off = 32; off > 0; off >>= 1) {
            ts += __shfl_xor(ts, off);
            td += __shfl_xor(td, off);
        }
        if (lane == 0) { aS2[n] = ts; aD2[n] = td; }
    }
}

// ---------------------------------------------------------------------------
// agg2: wave per node, fused bias + log_softmax
// ---------------------------------------------------------------------------
__global__ __launch_bounds__(256) void agg2_kernel(
    const float* __restrict__ h2, const float* __restrict__ aS2,
    const float* __restrict__ aD2, const int* __restrict__ offsets,
    const int* __restrict__ csr_src, const float* __restrict__ b2,
    float* __restrict__ out, int N)
{
    int lane = threadIdx.x & 63, wid = threadIdx.x >> 6;
    int n = blockIdx.x * 4 + wid;
    if (n >= N) return;
    int start = offsets[n], end = offsets[n + 1];
    float ad = aD2[n];

    float m = -INFINITY;
    for (int p = start + lane; p < end; p += 64)
        m = fmaxf(m, leaky(aS2[csr_src[p]] + ad));
#pragma unroll
    for (int off = 32; off > 0; off >>= 1) m = fmaxf(m, __shfl_xor(m, off));

    bool act = lane < OUTC;
    float acc = 0.f, denom = 0.f;
    for (int p = start; p < end; ++p) {
        int s = csr_src[p];
        float ex = __expf(leaky(aS2[s] + ad) - m);
        denom += ex;
        float hv = act ? h2[(size_t)s * OUTC + lane] : 0.f;
        acc += ex * hv;
    }
    float v = acc / (denom + EPSV) + (act ? b2[lane] : 0.f);

    float vm = act ? v : -INFINITY;
#pragma unroll
    for (int off = 32; off > 0; off >>= 1) vm = fmaxf(vm, __shfl_xor(vm, off));
    float ex2 = act ? __expf(v - vm) : 0.f;
    float tot = ex2;
#pragma unroll
    for (int off = 32; off > 0; off >>= 1) tot += __shfl_xor(tot, off);
    float res = v - vm - __logf(tot);
    if (act) out[(size_t)n * OUTC + lane] = res;
}

// ---------------------------------------------------------------------------
extern "C" void kernel_launch(void* const* d_in, const int* in_sizes, int n_in,
                              void* d_out, int out_size, void* d_ws, size_t ws_size,
                              hipStream_t stream)
{
    const float* x     = (const float*)d_in[0];
    const int*   ei    = (const int*)d_in[1];
    const float* W1    = (const float*)d_in[2];
    const float* attS1 = (const float*)d_in[3];
    const float* attD1 = (const float*)d_in[4];
    const float* b1    = (const float*)d_in[5];
    const float* W2    = (const float*)d_in[6];
    const float* attS2 = (const float*)d_in[7];
    const float* attD2 = (const float*)d_in[8];
    const float* b2    = (const float*)d_in[9];
    float* out = (float*)d_out;

    const int N    = in_sizes[0] / FIN;
    const int E    = in_sizes[1] / 2;
    const int Etot = E + N;

    char* ws = (char*)d_ws;
    size_t off = 0;
    auto take = [&](size_t bytes) -> char* {
        char* p = ws + off;
        off = (off + bytes + 255) & ~(size_t)255;
        return p;
    };
    float* h1      = (float*)take((size_t)N * H1DIM * 4);
    float* g1      = (float*)take((size_t)N * H1DIM * 4);
    float* aS1     = (float*)take((size_t)N * 4 * 4);
    float* aD1     = (float*)take((size_t)N * 4 * 4);
    float* h2      = (float*)take((size_t)N * OUTC * 4);
    float* aS2v    = (float*)take((size_t)N * 4);
    float* aD2v    = (float*)take((size_t)N * 4);
    int*   deg     = (int*)take((size_t)N * 4);
    int*   offsets = (int*)take((size_t)(N + 1) * 4);
    int*   cursor  = (int*)take((size_t)N * 4);
    int*   csr_src = (int*)take((size_t)Etot * 4);
    short* w1t     = (short*)take((size_t)FIN * H1DIM * 2);

    hipMemsetAsync(deg, 0, (size_t)N * 4, stream);
    hipMemsetAsync(cursor, 0, (size_t)N * 4, stream);

    cvt_w1_kernel<<<(FIN * H1DIM + 255) / 256, 256, 0, stream>>>(W1, w1t);
    gemm1_mfma_kernel<<<(N + 63) / 64, 256, 0, stream>>>(x, w1t, h1, N);
    scores1_kernel<<<(N * HEADS + 255) / 256, 256, 0, stream>>>(h1, attS1, attD1, aS1, aD1, N);
    degcount_kernel<<<(Etot + 255) / 256, 256, 0, stream>>>(ei, deg, E, Etot);
    scan_kernel<<<1, 1024, 0, stream>>>(deg, offsets, N);
    scatter_kernel<<<(Etot + 255) / 256, 256, 0, stream>>>(ei, offsets, cursor, csr_src, E, Etot);
    agg1_kernel<<<(N + 3) / 4, 256, 0, stream>>>(h1, aS1, aD1, offsets, csr_src, b1, g1, N);
    gemm2_kernel<<<(N + 31) / 32, 256, 0, stream>>>(g1, W2, attS2, attD2, h2, aS2v, aD2v, N);
    agg2_kernel<<<(N + 3) / 4, 256, 0, stream>>>(h2, aS2v, aD2v, offsets, csr_src, b2, out, N);
}

// Round 3
// 602.057 us; speedup vs baseline: 1.2351x; 1.1121x over previous
//
#include <hip/hip_runtime.h>
#include <math.h>

#define FIN   512
#define H1DIM 256
#define HEADS 4
#define CH    64
#define OUTC  40
#define NEG   0.2f
#define EPSV  1e-16f

__device__ __forceinline__ float leaky(float a) { return a > 0.f ? a : NEG * a; }

// round-to-nearest-even float -> bf16 (as short)
__device__ __forceinline__ short f2bf(float f) {
    unsigned u = __builtin_bit_cast(unsigned, f);
    u += 0x7FFFu + ((u >> 16) & 1u);
    return (short)(u >> 16);
}
__device__ __forceinline__ float bf2f(short s) {
    return __builtin_bit_cast(float, ((unsigned)(unsigned short)s) << 16);
}

typedef __attribute__((ext_vector_type(8))) short short8;
typedef __attribute__((ext_vector_type(4))) short short4_t;
typedef __attribute__((ext_vector_type(4))) float float4_t;

// ---------------------------------------------------------------------------
// x [N,512] fp32 -> xb bf16 (elementwise, memory-bound)
// ---------------------------------------------------------------------------
__global__ void cvt_x_kernel(const float* __restrict__ x, short* __restrict__ xb,
                             long long total4)
{
    long long i = (long long)blockIdx.x * 256 + threadIdx.x;
    if (i >= total4) return;
    float4 v = *(const float4*)&x[i * 4];
    short4_t o;
    o[0] = f2bf(v.x); o[1] = f2bf(v.y); o[2] = f2bf(v.z); o[3] = f2bf(v.w);
    *(short4_t*)&xb[i * 4] = o;
}

// ---------------------------------------------------------------------------
// W1 [512,256] fp32 -> w1t [256,512] bf16 (transposed)
// ---------------------------------------------------------------------------
__global__ void cvt_w1_kernel(const float* __restrict__ W1, short* __restrict__ w1t)
{
    int idx = blockIdx.x * 256 + threadIdx.x;
    if (idx >= FIN * H1DIM) return;
    int k = idx >> 8;
    int n = idx & 255;
    w1t[(size_t)n * FIN + k] = f2bf(W1[idx]);
}

// ---------------------------------------------------------------------------
// GEMM1 (MFMA bf16): h1b[N,256](bf16) = xb[N,512] @ W1[512,256]
// block=256 (4 waves), 64 rows/block, wave covers 64 cols (4x4 16x16 tiles).
// A-frag = one short8 load; B from w1t (L2-resident).
// A[m=lane&15][k=(lane>>4)*8+j]; C/D col=lane&15, row=(lane>>4)*4+reg.
// ---------------------------------------------------------------------------
__global__ __launch_bounds__(256) void gemm1_mfma_kernel(
    const short* __restrict__ xb, const short* __restrict__ w1t,
    short* __restrict__ h1b, int N)
{
    const int lane = threadIdx.x & 63;
    const int wid  = threadIdx.x >> 6;
    const int row0 = blockIdx.x * 64;
    const int col0 = wid * 64;
    const int quad = lane >> 4;
    const int m16  = lane & 15;

    float4_t acc[4][4];
#pragma unroll
    for (int i = 0; i < 4; ++i)
#pragma unroll
        for (int j = 0; j < 4; ++j) acc[i][j] = (float4_t){0.f, 0.f, 0.f, 0.f};

    const short* aptr[4];
#pragma unroll
    for (int i = 0; i < 4; ++i) {
        int r = row0 + i * 16 + m16;
        if (r >= N) r = N - 1;              // clamp; stores guarded
        aptr[i] = xb + (size_t)r * FIN + quad * 8;
    }
    const short* bptr[4];
#pragma unroll
    for (int j = 0; j < 4; ++j) {
        int c = col0 + j * 16 + m16;
        bptr[j] = w1t + (size_t)c * FIN + quad * 8;
    }

    for (int k = 0; k < FIN; k += 32) {
        short8 a[4], b[4];
#pragma unroll
        for (int i = 0; i < 4; ++i) a[i] = *(const short8*)(aptr[i] + k);
#pragma unroll
        for (int j = 0; j < 4; ++j) b[j] = *(const short8*)(bptr[j] + k);
#pragma unroll
        for (int i = 0; i < 4; ++i)
#pragma unroll
            for (int j = 0; j < 4; ++j)
                acc[i][j] = __builtin_amdgcn_mfma_f32_16x16x32_bf16(a[i], b[j], acc[i][j], 0, 0, 0);
    }

#pragma unroll
    for (int i = 0; i < 4; ++i) {
#pragma unroll
        for (int r = 0; r < 4; ++r) {
            int row = row0 + i * 16 + quad * 4 + r;
            if (row < N) {
#pragma unroll
                for (int j = 0; j < 4; ++j)
                    h1b[(size_t)row * H1DIM + col0 + j * 16 + m16] = f2bf(acc[i][j][r]);
            }
        }
    }
}

// ---------------------------------------------------------------------------
// scores1 from bf16 h1
// ---------------------------------------------------------------------------
__global__ void scores1_kernel(
    const short* __restrict__ h1b, const float* __restrict__ attS,
    const float* __restrict__ attD, float* __restrict__ aS,
    float* __restrict__ aD, int N)
{
    int i = blockIdx.x * blockDim.x + threadIdx.x;
    if (i >= N * HEADS) return;
    int n = i >> 2, h = i & 3;
    const short* hp = h1b + (size_t)n * H1DIM + h * CH;
    const float* sp = attS + h * CH;
    const float* dp = attD + h * CH;
    float s = 0.f, d = 0.f;
#pragma unroll
    for (int c = 0; c < CH; c += 8) {
        short8 hv = *(const short8*)&hp[c];
#pragma unroll
        for (int q = 0; q < 8; ++q) {
            float v = bf2f(hv[q]);
            s += v * sp[c + q];
            d += v * dp[c + q];
        }
    }
    aS[i] = s;
    aD[i] = d;
}

// ---------------------------------------------------------------------------
// CSR build
// ---------------------------------------------------------------------------
__global__ void degcount_kernel(const int* __restrict__ ei, int* __restrict__ deg,
                                int E, int Etot)
{
    int e = blockIdx.x * 256 + threadIdx.x;
    if (e >= Etot) return;
    int d = (e < E) ? ei[E + e] : (e - E);
    atomicAdd(&deg[d], 1);
}

// hierarchical scan: partial (per-block inclusive) -> tops -> add
__global__ __launch_bounds__(1024) void scan_partial_kernel(
    const int* __restrict__ deg, int* __restrict__ offsets,
    int* __restrict__ bsums, int N)
{
    __shared__ int wsums[16];
    __shared__ int excl[16];
    int tid = threadIdx.x, lane = tid & 63, wid = tid >> 6;
    int idx = blockIdx.x * 1024 + tid;
    int v = (idx < N) ? deg[idx] : 0;
    int sv = v;
#pragma unroll
    for (int off = 1; off < 64; off <<= 1) {
        int t = __shfl_up(sv, off, 64);
        if (lane >= off) sv += t;
    }
    if (lane == 63) wsums[wid] = sv;
    __syncthreads();
    if (wid == 0 && lane < 16) {
        int wv = wsums[lane];
        int sw = wv;
#pragma unroll
        for (int off = 1; off < 16; off <<= 1) {
            int t = __shfl_up(sw, off, 64);
            if (lane >= off) sw += t;
        }
        excl[lane] = sw - wv;
        if (lane == 15) bsums[blockIdx.x] = sw;
    }
    __syncthreads();
    if (idx < N) offsets[idx + 1] = sv + excl[wid];
}

__global__ __launch_bounds__(1024) void scan_tops_kernel(
    int* __restrict__ bsums, int* __restrict__ boffs, int nb)
{
    __shared__ int wsums[16];
    __shared__ int excl[16];
    int tid = threadIdx.x, lane = tid & 63, wid = tid >> 6;
    int v = (tid < nb) ? bsums[tid] : 0;
    int sv = v;
#pragma unroll
    for (int off = 1; off < 64; off <<= 1) {
        int t = __shfl_up(sv, off, 64);
        if (lane >= off) sv += t;
    }
    if (lane == 63) wsums[wid] = sv;
    __syncthreads();
    if (wid == 0 && lane < 16) {
        int wv = wsums[lane];
        int sw = wv;
#pragma unroll
        for (int off = 1; off < 16; off <<= 1) {
            int t = __shfl_up(sw, off, 64);
            if (lane >= off) sw += t;
        }
        excl[lane] = sw - wv;
    }
    __syncthreads();
    if (tid < nb) boffs[tid] = sv + excl[wid] - v;   // exclusive
}

__global__ __launch_bounds__(1024) void scan_add_kernel(
    int* __restrict__ offsets, const int* __restrict__ boffs, int N)
{
    int idx = blockIdx.x * 1024 + threadIdx.x;
    if (idx == 0) offsets[0] = 0;
    if (idx < N) offsets[idx + 1] += boffs[blockIdx.x];
}

__global__ void scatter_kernel(const int* __restrict__ ei, const int* __restrict__ offsets,
                               int* __restrict__ cursor, int* __restrict__ csr_src,
                               int E, int Etot)
{
    int e = blockIdx.x * 256 + threadIdx.x;
    if (e >= Etot) return;
    int s, d;
    if (e < E) { s = ei[e]; d = ei[E + e]; }
    else       { s = e - E; d = s; }
    int pos = offsets[d] + atomicAdd(&cursor[d], 1);
    csr_src[pos] = s;
}

// ---------------------------------------------------------------------------
// agg1: wave/node; softmax over in-edges; gather bf16 h1 rows; write bf16 g1
// ---------------------------------------------------------------------------
__global__ __launch_bounds__(256) void agg1_kernel(
    const short* __restrict__ h1b, const float* __restrict__ aS,
    const float* __restrict__ aD, const int* __restrict__ offsets,
    const int* __restrict__ csr_src, const float* __restrict__ b1,
    short* __restrict__ g1b, int N)
{
    int lane = threadIdx.x & 63, wid = threadIdx.x >> 6;
    int n = blockIdx.x * 4 + wid;
    if (n >= N) return;
    int start = offsets[n], end = offsets[n + 1];
    float4 ad = *(const float4*)&aD[(size_t)n * 4];

    float m0 = -INFINITY, m1 = -INFINITY, m2 = -INFINITY, m3 = -INFINITY;
    for (int p = start + lane; p < end; p += 64) {
        int s = csr_src[p];
        float4 as = *(const float4*)&aS[(size_t)s * 4];
        m0 = fmaxf(m0, leaky(as.x + ad.x));
        m1 = fmaxf(m1, leaky(as.y + ad.y));
        m2 = fmaxf(m2, leaky(as.z + ad.z));
        m3 = fmaxf(m3, leaky(as.w + ad.w));
    }
#pragma unroll
    for (int off = 32; off > 0; off >>= 1) {
        m0 = fmaxf(m0, __shfl_xor(m0, off));
        m1 = fmaxf(m1, __shfl_xor(m1, off));
        m2 = fmaxf(m2, __shfl_xor(m2, off));
        m3 = fmaxf(m3, __shfl_xor(m3, off));
    }
    int h = lane >> 4;
    float mh  = (h == 0) ? m0 : (h == 1) ? m1 : (h == 2) ? m2 : m3;
    float adh = (h == 0) ? ad.x : (h == 1) ? ad.y : (h == 2) ? ad.z : ad.w;

    float ac0 = 0.f, ac1 = 0.f, ac2 = 0.f, ac3 = 0.f, denom = 0.f;
    int cbase = lane * 4;
    for (int p = start; p < end; ++p) {
        int s = csr_src[p];
        float a = leaky(aS[(size_t)s * 4 + h] + adh);
        float ex = __expf(a - mh);
        denom += ex;
        short4_t hv = *(const short4_t*)&h1b[(size_t)s * H1DIM + cbase];
        ac0 += ex * bf2f(hv[0]);
        ac1 += ex * bf2f(hv[1]);
        ac2 += ex * bf2f(hv[2]);
        ac3 += ex * bf2f(hv[3]);
    }
    float inv = 1.f / (denom + EPSV);
    float4 bb = *(const float4*)&b1[cbase];
    float v0 = ac0 * inv + bb.x;
    float v1 = ac1 * inv + bb.y;
    float v2 = ac2 * inv + bb.z;
    float v3 = ac3 * inv + bb.w;
    v0 = v0 > 0.f ? v0 : expm1f(v0);
    v1 = v1 > 0.f ? v1 : expm1f(v1);
    v2 = v2 > 0.f ? v2 : expm1f(v2);
    v3 = v3 > 0.f ? v3 : expm1f(v3);
    short4_t o;
    o[0] = f2bf(v0); o[1] = f2bf(v1); o[2] = f2bf(v2); o[3] = f2bf(v3);
    *(short4_t*)&g1b[(size_t)n * H1DIM + cbase] = o;
}

// ---------------------------------------------------------------------------
// GEMM2: h2[N,40] = g1[N,256] @ W2[256,40]; fused a_src2/a_dst2 reductions
// g1 is bf16; staged to LDS as fp32.
// ---------------------------------------------------------------------------
__global__ __launch_bounds__(256) void gemm2_kernel(
    const short* __restrict__ g1b, const float* __restrict__ W2,
    const float* __restrict__ attS2, const float* __restrict__ attD2,
    float* __restrict__ h2, float* __restrict__ aS2, float* __restrict__ aD2, int N)
{
    __shared__ float rows[4][8][256];
    int lane = threadIdx.x & 63, wid = threadIdx.x >> 6;
    int nbase = blockIdx.x * 32 + wid * 8;
    bool act = lane < OUTC;
    int cc = act ? lane : 0;
    float attS = act ? attS2[lane] : 0.f;
    float attD = act ? attD2[lane] : 0.f;

#pragma unroll
    for (int i = 0; i < 8; ++i) {
        int n = nbase + i;
        float4 v = make_float4(0.f, 0.f, 0.f, 0.f);
        if (n < N) {
            short4_t hv = *(const short4_t*)&g1b[(size_t)n * H1DIM + lane * 4];
            v = make_float4(bf2f(hv[0]), bf2f(hv[1]), bf2f(hv[2]), bf2f(hv[3]));
        }
        *(float4*)&rows[wid][i][lane * 4] = v;
    }

    float acc[8];
#pragma unroll
    for (int i = 0; i < 8; ++i) acc[i] = 0.f;

    for (int k = 0; k < H1DIM; k += 4) {
        float w0 = W2[(size_t)(k + 0) * OUTC + cc];
        float w1 = W2[(size_t)(k + 1) * OUTC + cc];
        float w2 = W2[(size_t)(k + 2) * OUTC + cc];
        float w3 = W2[(size_t)(k + 3) * OUTC + cc];
#pragma unroll
        for (int i = 0; i < 8; ++i) {
            float4 g = *(const float4*)&rows[wid][i][k];
            acc[i] += g.x * w0 + g.y * w1 + g.z * w2 + g.w * w3;
        }
    }

#pragma unroll
    for (int i = 0; i < 8; ++i) {
        int n = nbase + i;
        if (n >= N) continue;   // wave-uniform
        if (act) h2[(size_t)n * OUTC + lane] = acc[i];
        float ts = act ? acc[i] * attS : 0.f;
        float td = act ? acc[i] * attD : 0.f;
#pragma unroll
        for (int off = 32; off > 0; off >>= 1) {
            ts += __shfl_xor(ts, off);
            td += __shfl_xor(td, off);
        }
        if (lane == 0) { aS2[n] = ts; aD2[n] = td; }
    }
}

// ---------------------------------------------------------------------------
// agg2: wave per node, fused bias + log_softmax
// ---------------------------------------------------------------------------
__global__ __launch_bounds__(256) void agg2_kernel(
    const float* __restrict__ h2, const float* __restrict__ aS2,
    const float* __restrict__ aD2, const int* __restrict__ offsets,
    const int* __restrict__ csr_src, const float* __restrict__ b2,
    float* __restrict__ out, int N)
{
    int lane = threadIdx.x & 63, wid = threadIdx.x >> 6;
    int n = blockIdx.x * 4 + wid;
    if (n >= N) return;
    int start = offsets[n], end = offsets[n + 1];
    float ad = aD2[n];

    float m = -INFINITY;
    for (int p = start + lane; p < end; p += 64)
        m = fmaxf(m, leaky(aS2[csr_src[p]] + ad));
#pragma unroll
    for (int off = 32; off > 0; off >>= 1) m = fmaxf(m, __shfl_xor(m, off));

    bool act = lane < OUTC;
    float acc = 0.f, denom = 0.f;
    for (int p = start; p < end; ++p) {
        int s = csr_src[p];
        float ex = __expf(leaky(aS2[s] + ad) - m);
        denom += ex;
        float hv = act ? h2[(size_t)s * OUTC + lane] : 0.f;
        acc += ex * hv;
    }
    float v = acc / (denom + EPSV) + (act ? b2[lane] : 0.f);

    float vm = act ? v : -INFINITY;
#pragma unroll
    for (int off = 32; off > 0; off >>= 1) vm = fmaxf(vm, __shfl_xor(vm, off));
    float ex2 = act ? __expf(v - vm) : 0.f;
    float tot = ex2;
#pragma unroll
    for (int off = 32; off > 0; off >>= 1) tot += __shfl_xor(tot, off);
    float res = v - vm - __logf(tot);
    if (act) out[(size_t)n * OUTC + lane] = res;
}

// ---------------------------------------------------------------------------
extern "C" void kernel_launch(void* const* d_in, const int* in_sizes, int n_in,
                              void* d_out, int out_size, void* d_ws, size_t ws_size,
                              hipStream_t stream)
{
    const float* x     = (const float*)d_in[0];
    const int*   ei    = (const int*)d_in[1];
    const float* W1    = (const float*)d_in[2];
    const float* attS1 = (const float*)d_in[3];
    const float* attD1 = (const float*)d_in[4];
    const float* b1    = (const float*)d_in[5];
    const float* W2    = (const float*)d_in[6];
    const float* attS2 = (const float*)d_in[7];
    const float* attD2 = (const float*)d_in[8];
    const float* b2    = (const float*)d_in[9];
    float* out = (float*)d_out;

    const int N    = in_sizes[0] / FIN;
    const int E    = in_sizes[1] / 2;
    const int Etot = E + N;
    const int nb   = (N + 1023) / 1024;

    char* ws = (char*)d_ws;
    size_t off = 0;
    auto take = [&](size_t bytes) -> char* {
        char* p = ws + off;
        off = (off + bytes + 255) & ~(size_t)255;
        return p;
    };
    short* xb      = (short*)take((size_t)N * FIN * 2);
    short* h1b     = (short*)take((size_t)N * H1DIM * 2);
    short* g1b     = (short*)take((size_t)N * H1DIM * 2);
    short* w1t     = (short*)take((size_t)FIN * H1DIM * 2);
    float* aS1     = (float*)take((size_t)N * 4 * 4);
    float* aD1     = (float*)take((size_t)N * 4 * 4);
    float* h2      = (float*)take((size_t)N * OUTC * 4);
    float* aS2v    = (float*)take((size_t)N * 4);
    float* aD2v    = (float*)take((size_t)N * 4);
    int*   deg     = (int*)take((size_t)N * 4);
    int*   offsets = (int*)take((size_t)(N + 1) * 4);
    int*   cursor  = (int*)take((size_t)N * 4);
    int*   bsums   = (int*)take((size_t)nb * 4);
    int*   boffs   = (int*)take((size_t)nb * 4);
    int*   csr_src = (int*)take((size_t)Etot * 4);

    hipMemsetAsync(deg, 0, (size_t)N * 4, stream);
    hipMemsetAsync(cursor, 0, (size_t)N * 4, stream);

    long long total4 = (long long)N * FIN / 4;
    cvt_x_kernel<<<(int)((total4 + 255) / 256), 256, 0, stream>>>(x, xb, total4);
    cvt_w1_kernel<<<(FIN * H1DIM + 255) / 256, 256, 0, stream>>>(W1, w1t);
    gemm1_mfma_kernel<<<(N + 63) / 64, 256, 0, stream>>>(xb, w1t, h1b, N);
    scores1_kernel<<<(N * HEADS + 255) / 256, 256, 0, stream>>>(h1b, attS1, attD1, aS1, aD1, N);
    degcount_kernel<<<(Etot + 255) / 256, 256, 0, stream>>>(ei, deg, E, Etot);
    scan_partial_kernel<<<nb, 1024, 0, stream>>>(deg, offsets, bsums, N);
    scan_tops_kernel<<<1, 1024, 0, stream>>>(bsums, boffs, nb);
    scan_add_kernel<<<nb, 1024, 0, stream>>>(offsets, boffs, N);
    scatter_kernel<<<(Etot + 255) / 256, 256, 0, stream>>>(ei, offsets, cursor, csr_src, E, Etot);
    agg1_kernel<<<(N + 3) / 4, 256, 0, stream>>>(h1b, aS1, aD1, offsets, csr_src, b1, g1b, N);
    gemm2_kernel<<<(N + 31) / 32, 256, 0, stream>>>(g1b, W2, attS2, attD2, h2, aS2v, aD2v, N);
    agg2_kernel<<<(N + 3) / 4, 256, 0, stream>>>(h2, aS2v, aD2v, offsets, csr_src, b2, out, N);
}

// Round 4
// 528.393 us; speedup vs baseline: 1.4072x; 1.1394x over previous
//
#include <hip/hip_runtime.h>
#include <math.h>

#define FIN   512
#define H1DIM 256
#define HEADS 4
#define CH    64
#define OUTC  40
#define NEG   0.2f
#define EPSV  1e-16f

__device__ __forceinline__ float leaky(float a) { return a > 0.f ? a : NEG * a; }

__device__ __forceinline__ short f2bf(float f) {
    unsigned u = __builtin_bit_cast(unsigned, f);
    u += 0x7FFFu + ((u >> 16) & 1u);
    return (short)(u >> 16);
}
__device__ __forceinline__ float bf2f(short s) {
    return __builtin_bit_cast(float, ((unsigned)(unsigned short)s) << 16);
}

typedef __attribute__((ext_vector_type(8))) short short8;
typedef __attribute__((ext_vector_type(4))) short short4_t;
typedef __attribute__((ext_vector_type(4))) float float4_t;

// ---------------------------------------------------------------------------
// x [N,512] fp32 -> xb bf16
// ---------------------------------------------------------------------------
__global__ void cvt_x_kernel(const float* __restrict__ x, short* __restrict__ xb,
                             long long total4)
{
    long long i = (long long)blockIdx.x * 256 + threadIdx.x;
    if (i >= total4) return;
    float4 v = *(const float4*)&x[i * 4];
    short4_t o;
    o[0] = f2bf(v.x); o[1] = f2bf(v.y); o[2] = f2bf(v.z); o[3] = f2bf(v.w);
    *(short4_t*)&xb[i * 4] = o;
}

// ---------------------------------------------------------------------------
// W1 [512,256] fp32 -> w1t [256,512] bf16 (transposed)
// ---------------------------------------------------------------------------
__global__ void cvt_w1_kernel(const float* __restrict__ W1, short* __restrict__ w1t)
{
    int idx = blockIdx.x * 256 + threadIdx.x;
    if (idx >= FIN * H1DIM) return;
    int k = idx >> 8;
    int n = idx & 255;
    w1t[(size_t)n * FIN + k] = f2bf(W1[idx]);
}

// ---------------------------------------------------------------------------
// GEMM1 (MFMA bf16) + fused per-head attention scores.
// block=256 (4 waves), 64 rows/block; wave w covers cols w*64..w*64+63 ==
// exactly head w's channels. Epilogue: 16-lane butterfly reduce gives
// aS1[row,h] / aD1[row,h] from fp32 accumulators.
// ---------------------------------------------------------------------------
__global__ __launch_bounds__(256) void gemm1_mfma_kernel(
    const short* __restrict__ xb, const short* __restrict__ w1t,
    const float* __restrict__ attS, const float* __restrict__ attD,
    short* __restrict__ h1b, float* __restrict__ aS1, float* __restrict__ aD1, int N)
{
    const int lane = threadIdx.x & 63;
    const int wid  = threadIdx.x >> 6;
    const int row0 = blockIdx.x * 64;
    const int col0 = wid * 64;
    const int quad = lane >> 4;
    const int m16  = lane & 15;

    float4_t acc[4][4];
#pragma unroll
    for (int i = 0; i < 4; ++i)
#pragma unroll
        for (int j = 0; j < 4; ++j) acc[i][j] = (float4_t){0.f, 0.f, 0.f, 0.f};

    const short* aptr[4];
#pragma unroll
    for (int i = 0; i < 4; ++i) {
        int r = row0 + i * 16 + m16;
        if (r >= N) r = N - 1;              // clamp; stores guarded
        aptr[i] = xb + (size_t)r * FIN + quad * 8;
    }
    const short* bptr[4];
#pragma unroll
    for (int j = 0; j < 4; ++j) {
        int c = col0 + j * 16 + m16;
        bptr[j] = w1t + (size_t)c * FIN + quad * 8;
    }

    for (int k = 0; k < FIN; k += 32) {
        short8 a[4], b[4];
#pragma unroll
        for (int i = 0; i < 4; ++i) a[i] = *(const short8*)(aptr[i] + k);
#pragma unroll
        for (int j = 0; j < 4; ++j) b[j] = *(const short8*)(bptr[j] + k);
#pragma unroll
        for (int i = 0; i < 4; ++i)
#pragma unroll
            for (int j = 0; j < 4; ++j)
                acc[i][j] = __builtin_amdgcn_mfma_f32_16x16x32_bf16(a[i], b[j], acc[i][j], 0, 0, 0);
    }

    float attSv[4], attDv[4];
#pragma unroll
    for (int j = 0; j < 4; ++j) {
        attSv[j] = attS[col0 + j * 16 + m16];
        attDv[j] = attD[col0 + j * 16 + m16];
    }

#pragma unroll
    for (int i = 0; i < 4; ++i) {
#pragma unroll
        for (int r = 0; r < 4; ++r) {
            int row = row0 + i * 16 + quad * 4 + r;
            // h1b store
            if (row < N) {
#pragma unroll
                for (int j = 0; j < 4; ++j)
                    h1b[(size_t)row * H1DIM + col0 + j * 16 + m16] = f2bf(acc[i][j][r]);
            }
            // fused scores: reduce over the 16 lanes of this quad group
            float ps = acc[i][0][r] * attSv[0] + acc[i][1][r] * attSv[1]
                     + acc[i][2][r] * attSv[2] + acc[i][3][r] * attSv[3];
            float pd = acc[i][0][r] * attDv[0] + acc[i][1][r] * attDv[1]
                     + acc[i][2][r] * attDv[2] + acc[i][3][r] * attDv[3];
#pragma unroll
            for (int off = 1; off < 16; off <<= 1) {
                ps += __shfl_xor(ps, off);
                pd += __shfl_xor(pd, off);
            }
            if (m16 == 0 && row < N) {
                aS1[(size_t)row * 4 + wid] = ps;
                aD1[(size_t)row * 4 + wid] = pd;
            }
        }
    }
}

// ---------------------------------------------------------------------------
// CSR build
// ---------------------------------------------------------------------------
__global__ void degcount_kernel(const int* __restrict__ ei, int* __restrict__ deg,
                                int E, int Etot)
{
    int e = blockIdx.x * 256 + threadIdx.x;
    if (e >= Etot) return;
    int d = (e < E) ? ei[E + e] : (e - E);
    atomicAdd(&deg[d], 1);
}

__global__ __launch_bounds__(1024) void scan_partial_kernel(
    const int* __restrict__ deg, int* __restrict__ offsets,
    int* __restrict__ bsums, int N)
{
    __shared__ int wsums[16];
    __shared__ int excl[16];
    int tid = threadIdx.x, lane = tid & 63, wid = tid >> 6;
    int idx = blockIdx.x * 1024 + tid;
    int v = (idx < N) ? deg[idx] : 0;
    int sv = v;
#pragma unroll
    for (int off = 1; off < 64; off <<= 1) {
        int t = __shfl_up(sv, off, 64);
        if (lane >= off) sv += t;
    }
    if (lane == 63) wsums[wid] = sv;
    __syncthreads();
    if (wid == 0 && lane < 16) {
        int wv = wsums[lane];
        int sw = wv;
#pragma unroll
        for (int off = 1; off < 16; off <<= 1) {
            int t = __shfl_up(sw, off, 64);
            if (lane >= off) sw += t;
        }
        excl[lane] = sw - wv;
        if (lane == 15) bsums[blockIdx.x] = sw;
    }
    __syncthreads();
    if (idx < N) offsets[idx + 1] = sv + excl[wid];
}

__global__ __launch_bounds__(1024) void scan_tops_kernel(
    int* __restrict__ bsums, int* __restrict__ boffs, int nb)
{
    __shared__ int wsums[16];
    __shared__ int excl[16];
    int tid = threadIdx.x, lane = tid & 63, wid = tid >> 6;
    int v = (tid < nb) ? bsums[tid] : 0;
    int sv = v;
#pragma unroll
    for (int off = 1; off < 64; off <<= 1) {
        int t = __shfl_up(sv, off, 64);
        if (lane >= off) sv += t;
    }
    if (lane == 63) wsums[wid] = sv;
    __syncthreads();
    if (wid == 0 && lane < 16) {
        int wv = wsums[lane];
        int sw = wv;
#pragma unroll
        for (int off = 1; off < 16; off <<= 1) {
            int t = __shfl_up(sw, off, 64);
            if (lane >= off) sw += t;
        }
        excl[lane] = sw - wv;
    }
    __syncthreads();
    if (tid < nb) boffs[tid] = sv + excl[wid] - v;
}

__global__ __launch_bounds__(1024) void scan_add_kernel(
    int* __restrict__ offsets, const int* __restrict__ boffs, int N)
{
    int idx = blockIdx.x * 1024 + threadIdx.x;
    if (idx == 0) offsets[0] = 0;
    if (idx < N) offsets[idx + 1] += boffs[blockIdx.x];
}

__global__ void scatter_kernel(const int* __restrict__ ei, const int* __restrict__ offsets,
                               int* __restrict__ cursor, int* __restrict__ csr_src,
                               int E, int Etot)
{
    int e = blockIdx.x * 256 + threadIdx.x;
    if (e >= Etot) return;
    int s, d;
    if (e < E) { s = ei[e]; d = ei[E + e]; }
    else       { s = e - E; d = s; }
    int pos = offsets[d] + atomicAdd(&cursor[d], 1);
    csr_src[pos] = s;
}

// ---------------------------------------------------------------------------
// attn1: per-node segment softmax weights (H=4), lane-parallel over edges.
// w1e[p*4+h] = exp(alpha - max); dinv1[n*4+h] = 1/(denom+eps)
// ---------------------------------------------------------------------------
__global__ __launch_bounds__(256) void attn1_kernel(
    const float* __restrict__ aS, const float* __restrict__ aD,
    const int* __restrict__ offsets, const int* __restrict__ csr_src,
    float* __restrict__ w1e, float* __restrict__ dinv1, int N)
{
    int lane = threadIdx.x & 63, wid = threadIdx.x >> 6;
    int n = blockIdx.x * 4 + wid;
    if (n >= N) return;
    int start = offsets[n], end = offsets[n + 1];
    float4 ad = *(const float4*)&aD[(size_t)n * 4];

    float m0 = -INFINITY, m1 = -INFINITY, m2 = -INFINITY, m3 = -INFINITY;
    for (int p = start + lane; p < end; p += 64) {
        int s = csr_src[p];
        float4 as = *(const float4*)&aS[(size_t)s * 4];
        m0 = fmaxf(m0, leaky(as.x + ad.x));
        m1 = fmaxf(m1, leaky(as.y + ad.y));
        m2 = fmaxf(m2, leaky(as.z + ad.z));
        m3 = fmaxf(m3, leaky(as.w + ad.w));
    }
#pragma unroll
    for (int off = 32; off > 0; off >>= 1) {
        m0 = fmaxf(m0, __shfl_xor(m0, off));
        m1 = fmaxf(m1, __shfl_xor(m1, off));
        m2 = fmaxf(m2, __shfl_xor(m2, off));
        m3 = fmaxf(m3, __shfl_xor(m3, off));
    }

    float d0 = 0.f, d1 = 0.f, d2 = 0.f, d3 = 0.f;
    for (int p = start + lane; p < end; p += 64) {
        int s = csr_src[p];
        float4 as = *(const float4*)&aS[(size_t)s * 4];
        float e0 = __expf(leaky(as.x + ad.x) - m0);
        float e1 = __expf(leaky(as.y + ad.y) - m1);
        float e2 = __expf(leaky(as.z + ad.z) - m2);
        float e3 = __expf(leaky(as.w + ad.w) - m3);
        d0 += e0; d1 += e1; d2 += e2; d3 += e3;
        *(float4*)&w1e[(size_t)p * 4] = make_float4(e0, e1, e2, e3);
    }
#pragma unroll
    for (int off = 32; off > 0; off >>= 1) {
        d0 += __shfl_xor(d0, off);
        d1 += __shfl_xor(d1, off);
        d2 += __shfl_xor(d2, off);
        d3 += __shfl_xor(d3, off);
    }
    if (lane == 0) {
        *(float4*)&dinv1[(size_t)n * 4] = make_float4(
            1.f / (d0 + EPSV), 1.f / (d1 + EPSV), 1.f / (d2 + EPSV), 1.f / (d3 + EPSV));
    }
}

// ---------------------------------------------------------------------------
// agg1: pure weighted gather, unroll x4 for MLP. g1b = ELU(acc*dinv + b1)
// ---------------------------------------------------------------------------
__global__ __launch_bounds__(256) void agg1_kernel(
    const short* __restrict__ h1b, const float* __restrict__ w1e,
    const float* __restrict__ dinv1, const int* __restrict__ offsets,
    const int* __restrict__ csr_src, const float* __restrict__ b1,
    short* __restrict__ g1b, int N)
{
    int lane = threadIdx.x & 63, wid = threadIdx.x >> 6;
    int n = blockIdx.x * 4 + wid;
    if (n >= N) return;
    int start = offsets[n], end = offsets[n + 1];
    int h = lane >> 4;
    int cbase = lane * 4;
    float4 di = *(const float4*)&dinv1[(size_t)n * 4];
    float invh = (h == 0) ? di.x : (h == 1) ? di.y : (h == 2) ? di.z : di.w;

    float ac0 = 0.f, ac1 = 0.f, ac2 = 0.f, ac3 = 0.f;
    int p = start;
    for (; p + 4 <= end; p += 4) {
        int s0 = csr_src[p], s1 = csr_src[p + 1], s2 = csr_src[p + 2], s3 = csr_src[p + 3];
        float w0 = w1e[(size_t)p * 4 + h];
        float w1 = w1e[(size_t)(p + 1) * 4 + h];
        float w2 = w1e[(size_t)(p + 2) * 4 + h];
        float w3 = w1e[(size_t)(p + 3) * 4 + h];
        short4_t r0 = *(const short4_t*)&h1b[(size_t)s0 * H1DIM + cbase];
        short4_t r1 = *(const short4_t*)&h1b[(size_t)s1 * H1DIM + cbase];
        short4_t r2 = *(const short4_t*)&h1b[(size_t)s2 * H1DIM + cbase];
        short4_t r3 = *(const short4_t*)&h1b[(size_t)s3 * H1DIM + cbase];
        ac0 += w0 * bf2f(r0[0]) + w1 * bf2f(r1[0]) + w2 * bf2f(r2[0]) + w3 * bf2f(r3[0]);
        ac1 += w0 * bf2f(r0[1]) + w1 * bf2f(r1[1]) + w2 * bf2f(r2[1]) + w3 * bf2f(r3[1]);
        ac2 += w0 * bf2f(r0[2]) + w1 * bf2f(r1[2]) + w2 * bf2f(r2[2]) + w3 * bf2f(r3[2]);
        ac3 += w0 * bf2f(r0[3]) + w1 * bf2f(r1[3]) + w2 * bf2f(r2[3]) + w3 * bf2f(r3[3]);
    }
    for (; p < end; ++p) {
        int s = csr_src[p];
        float w = w1e[(size_t)p * 4 + h];
        short4_t r = *(const short4_t*)&h1b[(size_t)s * H1DIM + cbase];
        ac0 += w * bf2f(r[0]);
        ac1 += w * bf2f(r[1]);
        ac2 += w * bf2f(r[2]);
        ac3 += w * bf2f(r[3]);
    }

    float4 bb = *(const float4*)&b1[cbase];
    float v0 = ac0 * invh + bb.x;
    float v1 = ac1 * invh + bb.y;
    float v2 = ac2 * invh + bb.z;
    float v3 = ac3 * invh + bb.w;
    v0 = v0 > 0.f ? v0 : expm1f(v0);
    v1 = v1 > 0.f ? v1 : expm1f(v1);
    v2 = v2 > 0.f ? v2 : expm1f(v2);
    v3 = v3 > 0.f ? v3 : expm1f(v3);
    short4_t o;
    o[0] = f2bf(v0); o[1] = f2bf(v1); o[2] = f2bf(v2); o[3] = f2bf(v3);
    *(short4_t*)&g1b[(size_t)n * H1DIM + cbase] = o;
}

// ---------------------------------------------------------------------------
// GEMM2: h2[N,40] = g1[N,256] @ W2[256,40]; fused a_src2/a_dst2
// ---------------------------------------------------------------------------
__global__ __launch_bounds__(256) void gemm2_kernel(
    const short* __restrict__ g1b, const float* __restrict__ W2,
    const float* __restrict__ attS2, const float* __restrict__ attD2,
    float* __restrict__ h2, float* __restrict__ aS2, float* __restrict__ aD2, int N)
{
    __shared__ float rows[4][8][256];
    int lane = threadIdx.x & 63, wid = threadIdx.x >> 6;
    int nbase = blockIdx.x * 32 + wid * 8;
    bool act = lane < OUTC;
    int cc = act ? lane : 0;
    float attS = act ? attS2[lane] : 0.f;
    float attD = act ? attD2[lane] : 0.f;

#pragma unroll
    for (int i = 0; i < 8; ++i) {
        int n = nbase + i;
        float4 v = make_float4(0.f, 0.f, 0.f, 0.f);
        if (n < N) {
            short4_t hv = *(const short4_t*)&g1b[(size_t)n * H1DIM + lane * 4];
            v = make_float4(bf2f(hv[0]), bf2f(hv[1]), bf2f(hv[2]), bf2f(hv[3]));
        }
        *(float4*)&rows[wid][i][lane * 4] = v;
    }

    float acc[8];
#pragma unroll
    for (int i = 0; i < 8; ++i) acc[i] = 0.f;

    for (int k = 0; k < H1DIM; k += 4) {
        float w0 = W2[(size_t)(k + 0) * OUTC + cc];
        float w1 = W2[(size_t)(k + 1) * OUTC + cc];
        float w2 = W2[(size_t)(k + 2) * OUTC + cc];
        float w3 = W2[(size_t)(k + 3) * OUTC + cc];
#pragma unroll
        for (int i = 0; i < 8; ++i) {
            float4 g = *(const float4*)&rows[wid][i][k];
            acc[i] += g.x * w0 + g.y * w1 + g.z * w2 + g.w * w3;
        }
    }

#pragma unroll
    for (int i = 0; i < 8; ++i) {
        int n = nbase + i;
        if (n >= N) continue;   // wave-uniform
        if (act) h2[(size_t)n * OUTC + lane] = acc[i];
        float ts = act ? acc[i] * attS : 0.f;
        float td = act ? acc[i] * attD : 0.f;
#pragma unroll
        for (int off = 32; off > 0; off >>= 1) {
            ts += __shfl_xor(ts, off);
            td += __shfl_xor(td, off);
        }
        if (lane == 0) { aS2[n] = ts; aD2[n] = td; }
    }
}

// ---------------------------------------------------------------------------
// attn2: H=1 segment softmax weights
// ---------------------------------------------------------------------------
__global__ __launch_bounds__(256) void attn2_kernel(
    const float* __restrict__ aS2, const float* __restrict__ aD2,
    const int* __restrict__ offsets, const int* __restrict__ csr_src,
    float* __restrict__ w2e, float* __restrict__ dinv2, int N)
{
    int lane = threadIdx.x & 63, wid = threadIdx.x >> 6;
    int n = blockIdx.x * 4 + wid;
    if (n >= N) return;
    int start = offsets[n], end = offsets[n + 1];
    float ad = aD2[n];

    float m = -INFINITY;
    for (int p = start + lane; p < end; p += 64)
        m = fmaxf(m, leaky(aS2[csr_src[p]] + ad));
#pragma unroll
    for (int off = 32; off > 0; off >>= 1) m = fmaxf(m, __shfl_xor(m, off));

    float d = 0.f;
    for (int p = start + lane; p < end; p += 64) {
        float e = __expf(leaky(aS2[csr_src[p]] + ad) - m);
        d += e;
        w2e[p] = e;
    }
#pragma unroll
    for (int off = 32; off > 0; off >>= 1) d += __shfl_xor(d, off);
    if (lane == 0) dinv2[n] = 1.f / (d + EPSV);
}

// ---------------------------------------------------------------------------
// agg2: weighted gather (unroll x4) + bias + log_softmax
// ---------------------------------------------------------------------------
__global__ __launch_bounds__(256) void agg2_kernel(
    const float* __restrict__ h2, const float* __restrict__ w2e,
    const float* __restrict__ dinv2, const int* __restrict__ offsets,
    const int* __restrict__ csr_src, const float* __restrict__ b2,
    float* __restrict__ out, int N)
{
    int lane = threadIdx.x & 63, wid = threadIdx.x >> 6;
    int n = blockIdx.x * 4 + wid;
    if (n >= N) return;
    int start = offsets[n], end = offsets[n + 1];
    bool act = lane < OUTC;
    int cc = act ? lane : 0;

    float acc = 0.f;
    int p = start;
    for (; p + 4 <= end; p += 4) {
        int s0 = csr_src[p], s1 = csr_src[p + 1], s2 = csr_src[p + 2], s3 = csr_src[p + 3];
        float w0 = w2e[p], w1 = w2e[p + 1], w2 = w2e[p + 2], w3 = w2e[p + 3];
        float h0 = h2[(size_t)s0 * OUTC + cc];
        float h1 = h2[(size_t)s1 * OUTC + cc];
        float hh2 = h2[(size_t)s2 * OUTC + cc];
        float h3 = h2[(size_t)s3 * OUTC + cc];
        acc += w0 * h0 + w1 * h1 + w2 * hh2 + w3 * h3;
    }
    for (; p < end; ++p)
        acc += w2e[p] * h2[(size_t)csr_src[p] * OUTC + cc];

    float v = acc * dinv2[n] + (act ? b2[lane] : 0.f);

    float vm = act ? v : -INFINITY;
#pragma unroll
    for (int off = 32; off > 0; off >>= 1) vm = fmaxf(vm, __shfl_xor(vm, off));
    float ex2 = act ? __expf(v - vm) : 0.f;
    float tot = ex2;
#pragma unroll
    for (int off = 32; off > 0; off >>= 1) tot += __shfl_xor(tot, off);
    float res = v - vm - __logf(tot);
    if (act) out[(size_t)n * OUTC + lane] = res;
}

// ---------------------------------------------------------------------------
extern "C" void kernel_launch(void* const* d_in, const int* in_sizes, int n_in,
                              void* d_out, int out_size, void* d_ws, size_t ws_size,
                              hipStream_t stream)
{
    const float* x     = (const float*)d_in[0];
    const int*   ei    = (const int*)d_in[1];
    const float* W1    = (const float*)d_in[2];
    const float* attS1 = (const float*)d_in[3];
    const float* attD1 = (const float*)d_in[4];
    const float* b1    = (const float*)d_in[5];
    const float* W2    = (const float*)d_in[6];
    const float* attS2 = (const float*)d_in[7];
    const float* attD2 = (const float*)d_in[8];
    const float* b2    = (const float*)d_in[9];
    float* out = (float*)d_out;

    const int N    = in_sizes[0] / FIN;
    const int E    = in_sizes[1] / 2;
    const int Etot = E + N;
    const int nb   = (N + 1023) / 1024;

    char* ws = (char*)d_ws;
    size_t off = 0;
    auto take = [&](size_t bytes) -> char* {
        char* p = ws + off;
        off = (off + bytes + 255) & ~(size_t)255;
        return p;
    };
    short* xb      = (short*)take((size_t)N * FIN * 2);
    short* h1b     = (short*)take((size_t)N * H1DIM * 2);
    short* g1b     = (short*)take((size_t)N * H1DIM * 2);
    short* w1t     = (short*)take((size_t)FIN * H1DIM * 2);
    float* aS1     = (float*)take((size_t)N * 4 * 4);
    float* aD1     = (float*)take((size_t)N * 4 * 4);
    float* h2      = (float*)take((size_t)N * OUTC * 4);
    float* aS2v    = (float*)take((size_t)N * 4);
    float* aD2v    = (float*)take((size_t)N * 4);
    int*   deg     = (int*)take((size_t)N * 4);
    int*   offsets = (int*)take((size_t)(N + 1) * 4);
    int*   cursor  = (int*)take((size_t)N * 4);
    int*   bsums   = (int*)take((size_t)nb * 4);
    int*   boffs   = (int*)take((size_t)nb * 4);
    int*   csr_src = (int*)take((size_t)Etot * 4);

    // attn-weight buffers alias xb (dead after gemm1)
    char* ab = (char*)xb;
    float* w1e   = (float*)ab;                       ab += ((size_t)Etot * 16 + 255) & ~(size_t)255;
    float* w2e   = (float*)ab;                       ab += ((size_t)Etot * 4 + 255) & ~(size_t)255;
    float* dinv1 = (float*)ab;                       ab += ((size_t)N * 16 + 255) & ~(size_t)255;
    float* dinv2 = (float*)ab;

    hipMemsetAsync(deg, 0, (size_t)N * 4, stream);
    hipMemsetAsync(cursor, 0, (size_t)N * 4, stream);

    long long total4 = (long long)N * FIN / 4;
    cvt_x_kernel<<<(int)((total4 + 255) / 256), 256, 0, stream>>>(x, xb, total4);
    cvt_w1_kernel<<<(FIN * H1DIM + 255) / 256, 256, 0, stream>>>(W1, w1t);
    gemm1_mfma_kernel<<<(N + 63) / 64, 256, 0, stream>>>(xb, w1t, attS1, attD1, h1b, aS1, aD1, N);
    degcount_kernel<<<(Etot + 255) / 256, 256, 0, stream>>>(ei, deg, E, Etot);
    scan_partial_kernel<<<nb, 1024, 0, stream>>>(deg, offsets, bsums, N);
    scan_tops_kernel<<<1, 1024, 0, stream>>>(bsums, boffs, nb);
    scan_add_kernel<<<nb, 1024, 0, stream>>>(offsets, boffs, N);
    scatter_kernel<<<(Etot + 255) / 256, 256, 0, stream>>>(ei, offsets, cursor, csr_src, E, Etot);
    attn1_kernel<<<(N + 3) / 4, 256, 0, stream>>>(aS1, aD1, offsets, csr_src, w1e, dinv1, N);
    agg1_kernel<<<(N + 3) / 4, 256, 0, stream>>>(h1b, w1e, dinv1, offsets, csr_src, b1, g1b, N);
    gemm2_kernel<<<(N + 31) / 32, 256, 0, stream>>>(g1b, W2, attS2, attD2, h2, aS2v, aD2v, N);
    attn2_kernel<<<(N + 3) / 4, 256, 0, stream>>>(aS2v, aD2v, offsets, csr_src, w2e, dinv2, N);
    agg2_kernel<<<(N + 3) / 4, 256, 0, stream>>>(h2, w2e, dinv2, offsets, csr_src, b2, out, N);
}